// Round 12
// baseline (87.022 us; speedup 1.0000x reference)
//
#include <hip/hip_runtime.h>
#include <stdint.h>

#define TT 128
#define BB 4096
#define HH 64
#define BC 16      // batch rows per block
#define XSTR 196   // xg LDS row stride (floats)
#define HSTR 72    // h LDS row stride (bf16 shorts)

typedef __attribute__((ext_vector_type(8))) short bf16x8;
typedef __attribute__((ext_vector_type(4))) float f32x4;

static __device__ __forceinline__ short f2bf(float f) {  // RNE, one-time W convert
  uint32_t u = __builtin_bit_cast(uint32_t, f);
  u += 0x7fffu + ((u >> 16) & 1u);
  return (short)(u >> 16);
}
static __device__ __forceinline__ uint32_t cvtpk(float a, float b) {
  uint32_t r;
  asm("v_cvt_pk_bf16_f32 %0, %1, %2" : "=v"(r) : "v"(a), "v"(b));
  return r;
}
static __device__ __forceinline__ float rcpf(float x) { return __builtin_amdgcn_rcpf(x); }
static __device__ __forceinline__ float sigm(float x) { return rcpf(1.0f + __expf(-x)); }
static __device__ __forceinline__ float tanhf_fast(float x) {
  float e = __expf(2.0f * x);
  return 1.0f - 2.0f * rcpf(e + 1.0f);
}
static __device__ __forceinline__ int imin2(int a, int b) { return a < b ? a : b; }

// Poll all 4 consumer-progress flags >= target, then fence LDS reads.
static __device__ __forceinline__ void poll_min4(volatile int* f, int target) {
  for (;;) {
    const int a = f[0], b = f[1], c = f[2], d = f[3];
    if (imin2(imin2(a, b), imin2(c, d)) >= target) break;
    __builtin_amdgcn_s_sleep(1);
  }
  asm volatile("s_waitcnt lgkmcnt(0)" ::: "memory");
}
static __device__ __forceinline__ void poll_one(volatile int* f, int target) {
  for (;;) {
    if (*f >= target) break;
    __builtin_amdgcn_s_sleep(1);
  }
  asm volatile("s_waitcnt lgkmcnt(0)" ::: "memory");
}
// data-writes-done fence before flag publish
static __device__ __forceinline__ void lds_drain() {
  asm volatile("s_waitcnt lgkmcnt(0)" ::: "memory");
}

#define MFMA __builtin_amdgcn_mfma_f32_16x16x32_bf16

__global__ __launch_bounds__(512) void gru_fused(
    const float* __restrict__ Hseq, const float* __restrict__ W_ih,
    const float* __restrict__ W_hh, const float* __restrict__ b_ih,
    const float* __restrict__ b_hh, const float* __restrict__ W_out,
    const float* __restrict__ b_out, float* __restrict__ out) {
  __shared__ __align__(16) short hsh[2][BC][HSTR];   // bf16 h, double buffered
  __shared__ __align__(16) float xgsh[4][BC][XSTR];  // fp32 x-preacts, 4-ring
  __shared__ float psum[4][BC];
  __shared__ int flagH[4];  // consumer wave progress (last finished step)
  __shared__ int flagP[4];  // producer wave progress (last produced step)
  volatile int* vH = (volatile int*)flagH;
  volatile int* vP = (volatile int*)flagP;

  const int tid = threadIdx.x;
  const int w   = tid >> 6;     // 0-3 consumers, 4-7 producers
  const int gw  = w & 3;        // gate-row chunk: j in [16gw, 16gw+16)
  const bool cons = (w < 4);
  const int l   = tid & 63;
  const int llo = l & 15;
  const int lhi = l >> 4;
  const int k0  = lhi * 8;
  const int bbase = blockIdx.x * BC;
  const f32x4 fz = {0.f, 0.f, 0.f, 0.f};

  if (tid < 4) { flagH[tid] = -1; flagP[tid] = -1; }
  for (int i = tid; i < BC * HSTR; i += 512) ((short*)hsh[0])[i] = 0;

  bf16x8 wa[3][2];
  f32x4 biasHN = fz;                           // consumer
  f32x4 biasPR = fz, biasPZ = fz, biasPN = fz; // producer

  if (cons) {
#pragma unroll
    for (int c = 0; c < 3; ++c) {
      const int grow = 16 * gw + 64 * c + llo;
#pragma unroll
      for (int hf = 0; hf < 2; ++hf) {
        const float* q = &W_hh[grow * 64 + hf * 32 + k0];
        bf16x8 b;
#pragma unroll
        for (int i = 0; i < 8; ++i) b[i] = f2bf(q[i]);
        wa[c][hf] = b;
      }
    }
#pragma unroll
    for (int r = 0; r < 4; ++r) biasHN[r] = b_hh[128 + 16 * gw + 4 * lhi + r];
  } else {
#pragma unroll
    for (int c = 0; c < 3; ++c) {
      const int grow = 16 * gw + 64 * c + llo;
#pragma unroll
      for (int hf = 0; hf < 2; ++hf) {
        const float* p = &W_ih[grow * 64 + hf * 32 + k0];
        bf16x8 a;
#pragma unroll
        for (int i = 0; i < 8; ++i) a[i] = f2bf(p[i]);
        wa[c][hf] = a;
      }
    }
#pragma unroll
    for (int r = 0; r < 4; ++r) {
      const int j = 16 * gw + 4 * lhi + r;
      biasPR[r] = b_ih[j] + b_hh[j];
      biasPZ[r] = b_ih[64 + j] + b_hh[64 + j];
      biasPN[r] = b_ih[128 + j];
    }
  }

  const float* xroot = Hseq + (size_t)(bbase + llo) * HH + k0;
  f32x4 hfp = fz;

  __syncthreads();  // one-time: flags + h0 visible to all waves

  if (!cons) {
    // ======== producer: free-running, gated only by consumer progress ========
    f32x4 xqA0, xqA1, xqA2, xqA3, xqB0, xqB1, xqB2, xqB3;
    // prologue: xg[0] -> slot0, xg[1] -> slot1
#pragma unroll
    for (int s = 0; s < 2; ++s) {
      const f32x4* pv = (const f32x4*)(xroot + (size_t)s * BB * HH);
      f32x4 q0 = pv[0], q1 = pv[1], q2 = pv[8], q3 = pv[9];
      union { uint32_t u[4]; bf16x8 v; } c0, c1;
      c0.u[0] = cvtpk(q0[0], q0[1]); c0.u[1] = cvtpk(q0[2], q0[3]);
      c0.u[2] = cvtpk(q1[0], q1[1]); c0.u[3] = cvtpk(q1[2], q1[3]);
      c1.u[0] = cvtpk(q2[0], q2[1]); c1.u[1] = cvtpk(q2[2], q2[3]);
      c1.u[2] = cvtpk(q3[0], q3[1]); c1.u[3] = cvtpk(q3[2], q3[3]);
      f32x4 cR = biasPR, cZ = biasPZ, cN = biasPN;
      cR = MFMA(wa[0][0], c0.v, cR, 0, 0, 0);
      cR = MFMA(wa[0][1], c1.v, cR, 0, 0, 0);
      cZ = MFMA(wa[1][0], c0.v, cZ, 0, 0, 0);
      cZ = MFMA(wa[1][1], c1.v, cZ, 0, 0, 0);
      cN = MFMA(wa[2][0], c0.v, cN, 0, 0, 0);
      cN = MFMA(wa[2][1], c1.v, cN, 0, 0, 0);
      *(f32x4*)&xgsh[s][llo][16 * gw + 4 * lhi]       = cR;
      *(f32x4*)&xgsh[s][llo][64 + 16 * gw + 4 * lhi]  = cZ;
      *(f32x4*)&xgsh[s][llo][128 + 16 * gw + 4 * lhi] = cN;
    }
    const f32x4* pa = (const f32x4*)(xroot + (size_t)2 * BB * HH);
    xqA0 = pa[0]; xqA1 = pa[1]; xqA2 = pa[8]; xqA3 = pa[9];
    const f32x4* pb = (const f32x4*)(xroot + (size_t)3 * BB * HH);
    xqB0 = pb[0]; xqB1 = pb[1]; xqB2 = pb[8]; xqB3 = pb[9];
    lds_drain();
    if (l == 0) vP[gw] = 1;

    // PBODY(u, XQ*): produce xg[u] into slot u&3; refill XQ <- x[u+2].
    // Slot u&3's previous tenant xg[u-4] was prefetched at consumer step u-5.
#define PBODY(U, XQ0, XQ1, XQ2, XQ3)                                          \
    {                                                                         \
      poll_min4(vH, (U) - 5);                                                 \
      union { uint32_t u[4]; bf16x8 v; } c0, c1;                              \
      c0.u[0] = cvtpk(XQ0[0], XQ0[1]); c0.u[1] = cvtpk(XQ0[2], XQ0[3]);       \
      c0.u[2] = cvtpk(XQ1[0], XQ1[1]); c0.u[3] = cvtpk(XQ1[2], XQ1[3]);       \
      c1.u[0] = cvtpk(XQ2[0], XQ2[1]); c1.u[1] = cvtpk(XQ2[2], XQ2[3]);       \
      c1.u[2] = cvtpk(XQ3[0], XQ3[1]); c1.u[3] = cvtpk(XQ3[2], XQ3[3]);       \
      {                                                                       \
        const int tn = imin2((U) + 2, TT - 1);                                \
        const f32x4* pv = (const f32x4*)(xroot + (size_t)tn * BB * HH);       \
        XQ0 = pv[0]; XQ1 = pv[1]; XQ2 = pv[8]; XQ3 = pv[9];                   \
      }                                                                       \
      f32x4 cR = biasPR, cZ = biasPZ, cN = biasPN;                            \
      cR = MFMA(wa[0][0], c0.v, cR, 0, 0, 0);                                 \
      cR = MFMA(wa[0][1], c1.v, cR, 0, 0, 0);                                 \
      cZ = MFMA(wa[1][0], c0.v, cZ, 0, 0, 0);                                 \
      cZ = MFMA(wa[1][1], c1.v, cZ, 0, 0, 0);                                 \
      cN = MFMA(wa[2][0], c0.v, cN, 0, 0, 0);                                 \
      cN = MFMA(wa[2][1], c1.v, cN, 0, 0, 0);                                 \
      const int sl = (U) & 3;                                                 \
      *(f32x4*)&xgsh[sl][llo][16 * gw + 4 * lhi]       = cR;                  \
      *(f32x4*)&xgsh[sl][llo][64 + 16 * gw + 4 * lhi]  = cZ;                  \
      *(f32x4*)&xgsh[sl][llo][128 + 16 * gw + 4 * lhi] = cN;                  \
      lds_drain();                                                            \
      if (l == 0) vP[gw] = (U);                                               \
    }

    for (int u = 2; u < TT; u += 2) {
      PBODY(u,     xqA0, xqA1, xqA2, xqA3)
      PBODY(u + 1, xqB0, xqB1, xqB2, xqB3)
    }
#undef PBODY
  } else {
    // ======== consumer: per-step h exchange among 4 waves via flags ========
    poll_one(&vP[gw], 0);
    f32x4 xc0 = *(const f32x4*)&xgsh[0][llo][16 * gw + 4 * lhi];
    f32x4 xc1 = *(const f32x4*)&xgsh[0][llo][64 + 16 * gw + 4 * lhi];
    f32x4 xc2 = *(const f32x4*)&xgsh[0][llo][128 + 16 * gw + 4 * lhi];

    for (int t = 0; t < TT; ++t) {
      poll_min4(vH, t - 1);  // all consumers finished step t-1 -> h[t] ready
      const bf16x8 hb0 = *(const bf16x8*)&hsh[t & 1][llo][k0];
      const bf16x8 hb1 = *(const bf16x8*)&hsh[t & 1][llo][k0 + 32];
      f32x4 aR  = MFMA(wa[0][0], hb0, xc0, 0, 0, 0);
      aR        = MFMA(wa[0][1], hb1, aR, 0, 0, 0);
      f32x4 aZ  = MFMA(wa[1][0], hb0, xc1, 0, 0, 0);
      aZ        = MFMA(wa[1][1], hb1, aZ, 0, 0, 0);
      f32x4 aHN = MFMA(wa[2][0], hb0, biasHN, 0, 0, 0);
      aHN       = MFMA(wa[2][1], hb1, aHN, 0, 0, 0);
      // prefetch xg[t+1] (pairwise sync; passes instantly in steady state,
      // latency hides under the MFMAs above)
      f32x4 xn0 = xc0, xn1 = xc1, xn2 = xc2;
      if (t + 1 < TT) {
        poll_one(&vP[gw], t + 1);
        const int nb = (t + 1) & 3;
        xn0 = *(const f32x4*)&xgsh[nb][llo][16 * gw + 4 * lhi];
        xn1 = *(const f32x4*)&xgsh[nb][llo][64 + 16 * gw + 4 * lhi];
        xn2 = *(const f32x4*)&xgsh[nb][llo][128 + 16 * gw + 4 * lhi];
      }
#pragma unroll
      for (int r = 0; r < 4; ++r) {
        const float rr = sigm(aR[r]);
        const float zz = sigm(aZ[r]);
        const float nn = tanhf_fast(xc2[r] + rr * aHN[r]);
        hfp[r] = nn + zz * (hfp[r] - nn);
      }
      uint2 pk;
      pk.x = cvtpk(hfp[0], hfp[1]);
      pk.y = cvtpk(hfp[2], hfp[3]);
      *(uint2*)&hsh[(t + 1) & 1][llo][16 * gw + 4 * lhi] = pk;
      lds_drain();
      if (l == 0) vH[w] = t;
      xc0 = xn0; xc1 = xn1; xc2 = xn2;
    }
  }

  __syncthreads();  // one-time: join for the head epilogue

  if (cons) {
    float part = 0.f;
#pragma unroll
    for (int r = 0; r < 4; ++r) part += hfp[r] * W_out[16 * gw + 4 * lhi + r];
    part += __shfl_xor(part, 16);
    part += __shfl_xor(part, 32);
    if (lhi == 0) psum[gw][llo] = part;
  }
  __syncthreads();
  if (tid < BC)
    out[bbase + tid] = psum[0][tid] + psum[1][tid] + psum[2][tid] + psum[3][tid] + b_out[0];
}

extern "C" void kernel_launch(void* const* d_in, const int* in_sizes, int n_in,
                              void* d_out, int out_size, void* d_ws, size_t ws_size,
                              hipStream_t stream) {
  (void)in_sizes; (void)n_in; (void)d_ws; (void)ws_size; (void)out_size;
  const float* Hseq  = (const float*)d_in[0];
  const float* W_ih  = (const float*)d_in[1];
  const float* W_hh  = (const float*)d_in[2];
  const float* b_ih  = (const float*)d_in[3];
  const float* b_hh  = (const float*)d_in[4];
  const float* W_out = (const float*)d_in[5];
  const float* b_out = (const float*)d_in[6];
  float* out = (float*)d_out;
  gru_fused<<<BB / BC, 512, 0, stream>>>(Hseq, W_ih, W_hh, b_ih, b_hh, W_out, b_out, out);
}

// Round 13
// 68.002 us; speedup vs baseline: 1.2797x; 1.2797x over previous
//
#include <hip/hip_runtime.h>
#include <stdint.h>

#define TT 128
#define BB 4096
#define HH 64
#define BC 16      // batch rows per block
#define HSTR 72    // h LDS row stride (bf16 shorts): 144B rows, 16B aligned

typedef __attribute__((ext_vector_type(8))) short bf16x8;
typedef __attribute__((ext_vector_type(4))) float f32x4;

static __device__ __forceinline__ short f2bf(float f) {  // RNE, one-time W convert
  uint32_t u = __builtin_bit_cast(uint32_t, f);
  u += 0x7fffu + ((u >> 16) & 1u);
  return (short)(u >> 16);
}
static __device__ __forceinline__ uint32_t cvtpk(float a, float b) {
  uint32_t r;
  asm("v_cvt_pk_bf16_f32 %0, %1, %2" : "=v"(r) : "v"(a), "v"(b));
  return r;  // lo16 = bf16(a), hi16 = bf16(b)
}
static __device__ __forceinline__ float bflo(uint32_t u) {
  return __builtin_bit_cast(float, u << 16);
}
static __device__ __forceinline__ float bfhi(uint32_t u) {
  return __builtin_bit_cast(float, u & 0xffff0000u);
}
static __device__ __forceinline__ float rcpf(float x) { return __builtin_amdgcn_rcpf(x); }
static __device__ __forceinline__ float sigm(float x) { return rcpf(1.0f + __expf(-x)); }
static __device__ __forceinline__ float tanhf_fast(float x) {
  float e = __expf(2.0f * x);
  return 1.0f - 2.0f * rcpf(e + 1.0f);
}

// lgkm-only barrier: LDS ops drain, global prefetch loads stay in flight.
static __device__ __forceinline__ void block_sync_lds() {
  asm volatile("" ::: "memory");
  asm volatile("s_waitcnt lgkmcnt(0)" ::: "memory");
  __builtin_amdgcn_s_barrier();
  asm volatile("" ::: "memory");
}

#define MFMA __builtin_amdgcn_mfma_f32_16x16x32_bf16

__global__ __launch_bounds__(512) void gru_fused(
    const float* __restrict__ Hseq, const float* __restrict__ W_ih,
    const float* __restrict__ W_hh, const float* __restrict__ b_ih,
    const float* __restrict__ b_hh, const float* __restrict__ W_out,
    const float* __restrict__ b_out, float* __restrict__ out) {
  __shared__ __align__(16) short hsh[2][BC][HSTR];  // bf16 h state, double buffered
  __shared__ __align__(16) uint4 rzsh[2][BC][17];   // bf16-packed R,Z preacts; pad->stride 68 dw
  __shared__ __align__(16) f32x4 xnsh[2][BC][17];   // fp32 XN preacts; pad->stride 68 dw
  __shared__ float psum[4][BC];

  const int tid = threadIdx.x;
  const int w   = tid >> 6;     // 0..7; 0-3 consumers (recurrence), 4-7 producers (x GEMM)
  const int gw  = w & 3;        // gate-row chunk: j in [16gw, 16gw+16)
  const bool cons = (w < 4);
  const int l   = tid & 63;
  const int llo = l & 15;       // batch col (B/D frags) or gate row (A frag)
  const int lhi = l >> 4;
  const int k0  = lhi * 8;
  const int slot = 4 * gw + lhi;  // handoff slot: pairwise (llo, lhi, gw) mapping
  const int bbase = blockIdx.x * BC;

  // zero h buffer 0 (h0 = 0)
  for (int i = tid; i < BC * HSTR; i += 512) ((short*)hsh[0])[i] = 0;

  bf16x8 wa[3][2];                       // consumer: W_hh frags; producer: W_ih frags
  f32x4 biasHN = {0, 0, 0, 0};           // consumer only
  f32x4 biasPR = {0, 0, 0, 0}, biasPZ = {0, 0, 0, 0}, biasPN = {0, 0, 0, 0};  // producer

  if (cons) {
#pragma unroll
    for (int c = 0; c < 3; ++c) {
      const int grow = 16 * gw + 64 * c + llo;
#pragma unroll
      for (int hf = 0; hf < 2; ++hf) {
        const float* q = &W_hh[grow * 64 + hf * 32 + k0];
        bf16x8 b;
#pragma unroll
        for (int i = 0; i < 8; ++i) b[i] = f2bf(q[i]);
        wa[c][hf] = b;
      }
    }
#pragma unroll
    for (int r = 0; r < 4; ++r) biasHN[r] = b_hh[128 + 16 * gw + 4 * lhi + r];
  } else {
#pragma unroll
    for (int c = 0; c < 3; ++c) {
      const int grow = 16 * gw + 64 * c + llo;
#pragma unroll
      for (int hf = 0; hf < 2; ++hf) {
        const float* p = &W_ih[grow * 64 + hf * 32 + k0];
        bf16x8 a;
#pragma unroll
        for (int i = 0; i < 8; ++i) a[i] = f2bf(p[i]);
        wa[c][hf] = a;
      }
    }
#pragma unroll
    for (int r = 0; r < 4; ++r) {
      const int j = 16 * gw + 4 * lhi + r;
      biasPR[r] = b_ih[j] + b_hh[j];
      biasPZ[r] = b_ih[64 + j] + b_hh[64 + j];
      biasPN[r] = b_ih[128 + j];
    }
  }

  const float* xroot = Hseq + (size_t)(bbase + llo) * HH + k0;  // per-lane t=0 base
  f32x4 xqA0, xqA1, xqA2, xqA3, xqB0, xqB1, xqB2, xqB3;  // producer 2-deep prefetch
  f32x4 hfp = {0.f, 0.f, 0.f, 0.f};  // consumer fp32 h (batch llo, 4 j's)

  // producer pre-step: xg[0] into buffer 0, then prefetch x[1] and x[2]
  if (!cons) {
    const f32x4* pv = (const f32x4*)xroot;  // x[0]
    f32x4 q0 = pv[0], q1 = pv[1], q2 = pv[8], q3 = pv[9];
    union { uint32_t u[4]; bf16x8 v; } c0, c1;
    c0.u[0] = cvtpk(q0[0], q0[1]); c0.u[1] = cvtpk(q0[2], q0[3]);
    c0.u[2] = cvtpk(q1[0], q1[1]); c0.u[3] = cvtpk(q1[2], q1[3]);
    c1.u[0] = cvtpk(q2[0], q2[1]); c1.u[1] = cvtpk(q2[2], q2[3]);
    c1.u[2] = cvtpk(q3[0], q3[1]); c1.u[3] = cvtpk(q3[2], q3[3]);
    f32x4 cR = biasPR, cZ = biasPZ, cN = biasPN;
    cR = MFMA(wa[0][0], c0.v, cR, 0, 0, 0);
    cR = MFMA(wa[0][1], c1.v, cR, 0, 0, 0);
    cZ = MFMA(wa[1][0], c0.v, cZ, 0, 0, 0);
    cZ = MFMA(wa[1][1], c1.v, cZ, 0, 0, 0);
    cN = MFMA(wa[2][0], c0.v, cN, 0, 0, 0);
    cN = MFMA(wa[2][1], c1.v, cN, 0, 0, 0);
    uint4 rz;
    rz.x = cvtpk(cR[0], cR[1]); rz.y = cvtpk(cR[2], cR[3]);
    rz.z = cvtpk(cZ[0], cZ[1]); rz.w = cvtpk(cZ[2], cZ[3]);
    rzsh[0][llo][slot] = rz;
    xnsh[0][llo][slot] = cN;
    const f32x4* pa = (const f32x4*)(xroot + (size_t)1 * BB * HH);  // x[1]
    xqA0 = pa[0]; xqA1 = pa[1]; xqA2 = pa[8]; xqA3 = pa[9];
    const f32x4* pb = (const f32x4*)(xroot + (size_t)2 * BB * HH);  // x[2]
    xqB0 = pb[0]; xqB1 = pb[1]; xqB2 = pb[8]; xqB3 = pb[9];
  }
  block_sync_lds();

  // Consumer step: 4 LDS reads (2 h, 1 rz, 1 xn); unpack bf16 R/Z; gates as R7.
#define CSTEP(RB, WB)                                                         \
  {                                                                           \
    const bf16x8 hb0 = *(const bf16x8*)&hsh[RB][llo][k0];                     \
    const bf16x8 hb1 = *(const bf16x8*)&hsh[RB][llo][k0 + 32];                \
    const uint4 rz   = rzsh[RB][llo][slot];                                   \
    const f32x4 aXN  = xnsh[RB][llo][slot];                                   \
    f32x4 xR, xZ;                                                             \
    xR[0] = bflo(rz.x); xR[1] = bfhi(rz.x);                                   \
    xR[2] = bflo(rz.y); xR[3] = bfhi(rz.y);                                   \
    xZ[0] = bflo(rz.z); xZ[1] = bfhi(rz.z);                                   \
    xZ[2] = bflo(rz.w); xZ[3] = bfhi(rz.w);                                   \
    f32x4 aR  = MFMA(wa[0][0], hb0, xR, 0, 0, 0);                             \
    aR        = MFMA(wa[0][1], hb1, aR, 0, 0, 0);                             \
    f32x4 aZ  = MFMA(wa[1][0], hb0, xZ, 0, 0, 0);                             \
    aZ        = MFMA(wa[1][1], hb1, aZ, 0, 0, 0);                             \
    f32x4 aHN = MFMA(wa[2][0], hb0, biasHN, 0, 0, 0);                         \
    aHN       = MFMA(wa[2][1], hb1, aHN, 0, 0, 0);                            \
    _Pragma("unroll")                                                         \
    for (int r = 0; r < 4; ++r) {                                             \
      const float rr = sigm(aR[r]);                                           \
      const float zz = sigm(aZ[r]);                                           \
      const float nn = tanhf_fast(aXN[r] + rr * aHN[r]);                      \
      hfp[r] = nn + zz * (hfp[r] - nn);                                       \
    }                                                                         \
    uint2 pk;                                                                 \
    pk.x = cvtpk(hfp[0], hfp[1]);                                             \
    pk.y = cvtpk(hfp[2], hfp[3]);                                             \
    *(uint2*)&hsh[WB][llo][16 * gw + 4 * lhi] = pk;                           \
  }

  // Producer step: build xg[next] into buffers [OB] from XQ regs; refill XQ<-x[TN].
#define PSTEP(OB, XQ0, XQ1, XQ2, XQ3, TN)                                     \
  {                                                                           \
    union { uint32_t u[4]; bf16x8 v; } c0, c1;                                \
    c0.u[0] = cvtpk(XQ0[0], XQ0[1]); c0.u[1] = cvtpk(XQ0[2], XQ0[3]);         \
    c0.u[2] = cvtpk(XQ1[0], XQ1[1]); c0.u[3] = cvtpk(XQ1[2], XQ1[3]);         \
    c1.u[0] = cvtpk(XQ2[0], XQ2[1]); c1.u[1] = cvtpk(XQ2[2], XQ2[3]);         \
    c1.u[2] = cvtpk(XQ3[0], XQ3[1]); c1.u[3] = cvtpk(XQ3[2], XQ3[3]);         \
    {                                                                         \
      const int tn = (TN) < TT ? (TN) : (TT - 1);                             \
      const f32x4* pv = (const f32x4*)(xroot + (size_t)tn * BB * HH);         \
      XQ0 = pv[0]; XQ1 = pv[1]; XQ2 = pv[8]; XQ3 = pv[9];                     \
    }                                                                         \
    f32x4 cR = biasPR, cZ = biasPZ, cN = biasPN;                              \
    cR = MFMA(wa[0][0], c0.v, cR, 0, 0, 0);                                   \
    cR = MFMA(wa[0][1], c1.v, cR, 0, 0, 0);                                   \
    cZ = MFMA(wa[1][0], c0.v, cZ, 0, 0, 0);                                   \
    cZ = MFMA(wa[1][1], c1.v, cZ, 0, 0, 0);                                   \
    cN = MFMA(wa[2][0], c0.v, cN, 0, 0, 0);                                   \
    cN = MFMA(wa[2][1], c1.v, cN, 0, 0, 0);                                   \
    uint4 rz;                                                                 \
    rz.x = cvtpk(cR[0], cR[1]); rz.y = cvtpk(cR[2], cR[3]);                   \
    rz.z = cvtpk(cZ[0], cZ[1]); rz.w = cvtpk(cZ[2], cZ[3]);                   \
    rzsh[OB][llo][slot] = rz;                                                 \
    xnsh[OB][llo][slot] = cN;                                                 \
  }

  for (int t = 0; t < TT; t += 2) {
    if (cons) { CSTEP(0, 1) } else { PSTEP(1, xqA0, xqA1, xqA2, xqA3, t + 3) }
    block_sync_lds();
    if (cons) { CSTEP(1, 0) } else { PSTEP(0, xqB0, xqB1, xqB2, xqB3, t + 4) }
    block_sync_lds();
  }
#undef CSTEP
#undef PSTEP

  // ---- head: out[b] = h_last[b,:] . W_out + b_out ----
  if (cons) {
    float part = 0.f;
#pragma unroll
    for (int r = 0; r < 4; ++r) part += hfp[r] * W_out[16 * gw + 4 * lhi + r];
    part += __shfl_xor(part, 16);
    part += __shfl_xor(part, 32);
    if (lhi == 0) psum[gw][llo] = part;
  }
  block_sync_lds();
  if (tid < BC)
    out[bbase + tid] = psum[0][tid] + psum[1][tid] + psum[2][tid] + psum[3][tid] + b_out[0];
}

extern "C" void kernel_launch(void* const* d_in, const int* in_sizes, int n_in,
                              void* d_out, int out_size, void* d_ws, size_t ws_size,
                              hipStream_t stream) {
  (void)in_sizes; (void)n_in; (void)d_ws; (void)ws_size; (void)out_size;
  const float* Hseq  = (const float*)d_in[0];
  const float* W_ih  = (const float*)d_in[1];
  const float* W_hh  = (const float*)d_in[2];
  const float* b_ih  = (const float*)d_in[3];
  const float* b_hh  = (const float*)d_in[4];
  const float* W_out = (const float*)d_in[5];
  const float* b_out = (const float*)d_in[6];
  float* out = (float*)d_out;
  gru_fused<<<BB / BC, 512, 0, stream>>>(Hseq, W_ih, W_hh, b_ih, b_hh, W_out, b_out, out);
}